// Round 9
// baseline (218.430 us; speedup 1.0000x reference)
//
#include <hip/hip_runtime.h>
#include <hip/hip_bf16.h>
#include <stdint.h>

typedef short v8s __attribute__((ext_vector_type(8)));
typedef float v4f __attribute__((ext_vector_type(4)));

// ---------------- common helpers ----------------
__device__ __forceinline__ uint16_t f2b(float f) {
    __hip_bfloat16 h = __float2bfloat16(f);
    return *reinterpret_cast<uint16_t*>(&h);
}
__device__ __forceinline__ uint32_t pkbf(float lo, float hi) {
    return (uint32_t)f2b(lo) | ((uint32_t)f2b(hi) << 16);
}
__device__ __forceinline__ float b2f(uint16_t h) {
    return __uint_as_float(((uint32_t)h) << 16);
}

// ws weight-fragment bases (16B units): conv0 50 frags, conv1 36, conv2 72 (x64 lanes)
#define WS0_U 0
#define WS1_U 3200
#define WS2_U 5504
#define WS_UNITS 10112
#define WS_W_BYTES (WS_UNITS * 16)          // 161,792

// activation slots in ws (per sample): slotA = X1 then X3 (98,304B), slotB = X2 (98,304B)
#define SLOT_BYTES 196608
#define ACT_BASE   WS_W_BYTES

// ---------------- weight prep: pack A-fragments (bf16) into d_ws ----------------
__global__ void prep_weights(const float* __restrict__ w0,
                             const float* __restrict__ w1,
                             const float* __restrict__ w2,
                             uint8_t* __restrict__ ws)
{
    int u = blockIdx.x * 256 + threadIdx.x;
    if (u >= WS_UNITS) return;
    int l = u & 63, fid = u >> 6;
    const float* src; int IC, KS_, t, kf, m;
    if (fid < 50)      { src = w0; IC = 26; KS_ = 5; t = fid >> 1; kf = 0; m = fid & 1; }
    else if (fid < 86) { int v = fid - 50; src = w1; IC = 32; KS_ = 3; t = v >> 2; kf = 0; m = v & 3; }
    else               { int v = fid - 86; src = w2; IC = 64; KS_ = 3; t = v >> 3; kf = (v >> 2) & 1; m = v & 3; }
    int oc = m * 16 + (l & 15);
    int kb = kf * 32 + ((l >> 4) * 8);
    int ky = t / KS_, kx = t - ky * KS_;
    v8s out;
#pragma unroll
    for (int j = 0; j < 8; ++j) {
        int k = kb + j;
        float v = (k < IC) ? src[((oc * IC + k) * KS_ + ky) * KS_ + kx] : 0.f;
        out[j] = (short)f2b(v);
    }
    ((v8s*)ws)[u] = out;
}

// ---------------- conv core, 6 tiles/wave (kernels A and B) ----------------
template<int MT, int TAPS, int KS, int PAD, int IN_SH, int IN_ROWS,
         int WS_BASE, int MBASE, int MT_TOT>
__device__ __forceinline__ void conv_core6(const uint8_t* smem, const v8s* __restrict__ wsv,
                                           int l, const int* px, const int* py,
                                           v4f (&acc)[MT][6])
{
    const int kgoff = ((l >> 4) << 4);
    constexpr int MSK = (IN_SH == 7) ? 7 : 3;
    for (int t = 0; t < TAPS; ++t) {
        const int ky = t / KS, kx = t - ky * KS;
        const int dx = ky - PAD, dy = kx - PAD;
        v8s af[MT];
#pragma unroll
        for (int m = 0; m < MT; ++m)
            af[m] = wsv[WS_BASE + (t * MT_TOT + MBASE + m) * 64 + l];
#pragma unroll
        for (int i = 0; i < 6; ++i) {
            const int xi = px[i] + dx;
            const int rowp = xi * IN_ROWS + py[i] + dy + PAD;
            int a = ((rowp << IN_SH) | kgoff) ^ ((rowp & MSK) << 4);
            a = ((unsigned)xi < 32u) ? a : kgoff;            // x OOB -> zeroed row 0
            const v8s bf0 = *(const v8s*)(smem + a);
#pragma unroll
            for (int m = 0; m < MT; ++m)
                acc[m][i] = __builtin_amdgcn_mfma_f32_16x16x32_bf16(af[m], bf0, acc[m][i], 0, 0, 0);
        }
    }
}

// epilogue to GLOBAL (bf16, row stride OSTRIDE bytes, channel base cbase)
template<int MT, int OSTRIDE>
__device__ __forceinline__ void epi6_global(uint8_t* __restrict__ gout,
                                            const float* __restrict__ bias, int bbase,
                                            v4f (&acc)[MT][6], const int* px, const int* py,
                                            int kg, int cbase)
{
#pragma unroll
    for (int m = 0; m < MT; ++m) {
        const float* bp = bias + (bbase + m) * 16 + kg * 4;
        const float bb0 = bp[0], bb1 = bp[1], bb2 = bp[2], bb3 = bp[3];
#pragma unroll
        for (int i = 0; i < 6; ++i) {
            const float v0 = fmaxf(acc[m][i][0] + bb0, 0.f);
            const float v1 = fmaxf(acc[m][i][1] + bb1, 0.f);
            const float v2 = fmaxf(acc[m][i][2] + bb2, 0.f);
            const float v3 = fmaxf(acc[m][i][3] + bb3, 0.f);
            uint2 pk;
            pk.x = pkbf(v0, v1);
            pk.y = pkbf(v2, v3);
            const int p = px[i] * 24 + py[i];
            *(uint2*)(gout + p * OSTRIDE + (cbase + m * 16 + kg * 4) * 2) = pk;
        }
    }
}

// ======================= Kernel A: scatter + conv0 =======================
// grid 512 (sample), TPB 512. LDS: X0 [896 rows][64B], swz (row&3)<<4 = 57,344B.
__global__ __launch_bounds__(512)
void k_scatter_conv0(const int* __restrict__ rpos,
                     const float* __restrict__ rooms,
                     const float* __restrict__ emb,
                     const float* __restrict__ b0,
                     const uint8_t* __restrict__ ws,
                     uint8_t* __restrict__ act)
{
    __shared__ __align__(16) uint8_t smem[57344];
    const int tid = threadIdx.x, n = blockIdx.x;
    const int* rp = rpos + n * 128;
    const v8s* wsv = (const v8s*)ws;
    uint8_t* x1g = act + ACT_BASE + (size_t)n * SLOT_BYTES;        // [768][32c] bf16

    // ---- scatter: one padded row per thread (896 rows) ----
    for (int u = tid; u < 896; u += 512) {
        const int x = (u * 2341) >> 16;            // u / 28
        const int yp = u - x * 28;
        const int swz = (u & 3) << 4;
        if (yp >= 2 && yp < 26) {
            const int y = yp - 2;
            float a[26];
#pragma unroll
            for (int c = 0; c < 26; ++c) a[c] = 0.f;
            a[9] = 1.f;
            for (int r = 0; r < 64; ++r) {
                const int ci = x - rp[2 * r], cj = y - rp[2 * r + 1];
                if ((unsigned)ci < 6u && (unsigned)cj < 6u) {
                    const int cell = ci * 6 + cj;
                    const float* rr = rooms + r * 324;
                    const float mv = rr[cell];
                    if (mv != 0.f) {
#pragma unroll
                        for (int c = 0; c < 9; ++c) a[c] += rr[c * 36 + cell];
                        const float* er = emb + r * 16;
#pragma unroll
                        for (int e = 0; e < 16; ++e) a[10 + e] = fmaf(er[e], mv, a[10 + e]);
                    }
                }
            }
#pragma unroll
            for (int cg = 0; cg < 4; ++cg) {
                float c0 = (cg * 8 + 0 < 26) ? a[(cg * 8 + 0 < 26) ? cg * 8 + 0 : 0] : 0.f;
                float c1 = (cg * 8 + 1 < 26) ? a[(cg * 8 + 1 < 26) ? cg * 8 + 1 : 0] : 0.f;
                float c2 = (cg * 8 + 2 < 26) ? a[(cg * 8 + 2 < 26) ? cg * 8 + 2 : 0] : 0.f;
                float c3 = (cg * 8 + 3 < 26) ? a[(cg * 8 + 3 < 26) ? cg * 8 + 3 : 0] : 0.f;
                float c4 = (cg * 8 + 4 < 26) ? a[(cg * 8 + 4 < 26) ? cg * 8 + 4 : 0] : 0.f;
                float c5 = (cg * 8 + 5 < 26) ? a[(cg * 8 + 5 < 26) ? cg * 8 + 5 : 0] : 0.f;
                float c6 = (cg * 8 + 6 < 26) ? a[(cg * 8 + 6 < 26) ? cg * 8 + 6 : 0] : 0.f;
                float c7 = (cg * 8 + 7 < 26) ? a[(cg * 8 + 7 < 26) ? cg * 8 + 7 : 0] : 0.f;
                uint2 p0, p1;
                p0.x = pkbf(c0, c1); p0.y = pkbf(c2, c3);
                p1.x = pkbf(c4, c5); p1.y = pkbf(c6, c7);
                const int a0 = (((u << 6) | (cg << 4)) ^ swz);
                *(uint2*)(smem + a0)     = p0;
                *(uint2*)(smem + a0 + 8) = p1;
            }
        } else {
#pragma unroll
            for (int cg = 0; cg < 4; ++cg)
                *(v8s*)(smem + (((u << 6) | (cg << 4)) ^ swz)) = (v8s){0,0,0,0,0,0,0,0};
        }
    }
    __syncthreads();

    // ---- conv0: 26->32, 5x5, MT=2, 6 tiles/wave ----
    const int l = tid & 63, wv = tid >> 6, kg = l >> 4;
    int px[6], py[6];
#pragma unroll
    for (int i = 0; i < 6; ++i) {
        const int p = (wv * 6 + i) * 16 + (l & 15);
        const int x = (p * 2731) >> 16;
        px[i] = x; py[i] = p - x * 24;
    }
    v4f acc[2][6];
#pragma unroll
    for (int m = 0; m < 2; ++m)
#pragma unroll
        for (int i = 0; i < 6; ++i) acc[m][i] = (v4f){0.f, 0.f, 0.f, 0.f};
    conv_core6<2, 25, 5, 2, 6, 28, WS0_U, 0, 2>(smem, wsv, l, px, py, acc);
    epi6_global<2, 64>(x1g, b0, 0, acc, px, py, kg, 0);
}

// ======================= Kernel B: conv1 (per oc-half) =======================
// grid 1024 (n = bid>>1, h = bid&1), TPB 512. LDS: X1 [832 rows][64B] swz&3 = 53,248B.
__global__ __launch_bounds__(512)
void k_conv1(const float* __restrict__ b1,
             const uint8_t* __restrict__ ws,
             uint8_t* __restrict__ act)
{
    __shared__ __align__(16) uint8_t smem[53248];
    const int tid = threadIdx.x;
    const int n = blockIdx.x >> 1, h = blockIdx.x & 1;
    const v8s* wsv = (const v8s*)ws;
    const uint8_t* x1g = act + ACT_BASE + (size_t)n * SLOT_BYTES;           // [768][32c]
    uint8_t*       x2g = act + ACT_BASE + (size_t)n * SLOT_BYTES + 98304;   // [768][64c]

    // stage X1 -> LDS (insert y-pad rows)
    for (int u = tid; u < 3328; u += 512) {
        const int row = u >> 2, slot = u & 3;
        const int x = (row * 2521) >> 16;          // row / 26
        const int yp = row - x * 26;
        v8s v = {0,0,0,0,0,0,0,0};
        if (yp >= 1 && yp < 25) {
            const int p = x * 24 + yp - 1;
            v = *(const v8s*)(x1g + p * 64 + slot * 16);
        }
        *(v8s*)(smem + (((row << 6) | (slot << 4)) ^ ((row & 3) << 4))) = v;
    }
    __syncthreads();

    const int l = tid & 63, wv = tid >> 6, kg = l >> 4;
    int px[6], py[6];
#pragma unroll
    for (int i = 0; i < 6; ++i) {
        const int p = (wv * 6 + i) * 16 + (l & 15);
        const int x = (p * 2731) >> 16;
        px[i] = x; py[i] = p - x * 24;
    }
    v4f acc[2][6];
#pragma unroll
    for (int m = 0; m < 2; ++m)
#pragma unroll
        for (int i = 0; i < 6; ++i) acc[m][i] = (v4f){0.f, 0.f, 0.f, 0.f};
    conv_core6<2, 9, 3, 1, 6, 26, WS1_U, 0, 4>(smem, wsv, l, px, py,
                                               acc);
    // NOTE: MBASE must be 2*h — handled by re-dispatch below
    // (dead store elimination: we re-run with correct MBASE via if)
    if (h == 0) {
        epi6_global<2, 128>(x2g, b1, 0, acc, px, py, kg, 0);
    } else {
        // recompute with MBASE=2 (h==1 blocks skip the h0 accumulation result)
#pragma unroll
        for (int m = 0; m < 2; ++m)
#pragma unroll
            for (int i = 0; i < 6; ++i) acc[m][i] = (v4f){0.f, 0.f, 0.f, 0.f};
        conv_core6<2, 9, 3, 1, 6, 26, WS1_U, 2, 4>(smem, wsv, l, px, py, acc);
        epi6_global<2, 128>(x2g, b1, 2, acc, px, py, kg, 32);
    }
}

// ======================= Kernel C: conv2 (per 8-wide x-slab) =======================
// grid 2048 (n = bid>>2, s = bid&3), TPB 256. LDS slab: [10 xs][26 y][128B] swz&7 = 33,280B.
__global__ __launch_bounds__(256)
void k_conv2(const float* __restrict__ b2,
             const uint8_t* __restrict__ ws,
             uint8_t* __restrict__ act)
{
    __shared__ __align__(16) uint8_t smem[33280];
    const int tid = threadIdx.x;
    const int n = blockIdx.x >> 2, s = blockIdx.x & 3;
    const int x0 = s * 8;
    const v8s* wsv = (const v8s*)ws;
    const uint8_t* x2g = act + ACT_BASE + (size_t)n * SLOT_BYTES + 98304;   // [768][64c]
    uint8_t*       x3g = act + ACT_BASE + (size_t)n * SLOT_BYTES;           // [768][64c]

    // stage slab: rows rho = xs*26 + y', xs in [0,10) <-> gx = x0 + xs - 1
    for (int u = tid; u < 2080; u += 256) {
        const int rho = u >> 3, slot = u & 7;
        const int xs = (rho * 2521) >> 16;         // rho / 26
        const int yp = rho - xs * 26;
        const int gx = x0 + xs - 1;
        v8s v = {0,0,0,0,0,0,0,0};
        if ((unsigned)gx < 32u && yp >= 1 && yp < 25) {
            const int p = gx * 24 + yp - 1;
            v = *(const v8s*)(x2g + p * 128 + slot * 16);
        }
        *(v8s*)(smem + (((rho << 7) | (slot << 4)) ^ ((rho & 7) << 4))) = v;
    }
    __syncthreads();

    // conv2: 64->64, 3x3, MT=4, KF=2, 3 tiles/wave over 192 local pixels
    const int l = tid & 63, wv = tid >> 6, kg = l >> 4;
    const int kgoff = kg << 4;
    int lx[3], ly[3];
#pragma unroll
    for (int i = 0; i < 3; ++i) {
        const int p = (wv * 3 + i) * 16 + (l & 15);     // 0..191
        const int x = (p * 2731) >> 16;                 // p / 24
        lx[i] = x; ly[i] = p - x * 24;
    }
    v4f acc[4][3];
#pragma unroll
    for (int m = 0; m < 4; ++m)
#pragma unroll
        for (int i = 0; i < 3; ++i) acc[m][i] = (v4f){0.f, 0.f, 0.f, 0.f};

    for (int t = 0; t < 9; ++t) {
        const int ky = t / 3, kx = t - ky * 3;
        const int dx = ky - 1, dy = kx - 1;
        v8s af[4][2];
#pragma unroll
        for (int m = 0; m < 4; ++m)
#pragma unroll
            for (int kf = 0; kf < 2; ++kf)
                af[m][kf] = wsv[WS2_U + ((t * 2 + kf) * 4 + m) * 64 + l];
#pragma unroll
        for (int i = 0; i < 3; ++i) {
            const int gx = x0 + lx[i] + dx;
            const int rho = (lx[i] + dx + 1) * 26 + ly[i] + dy + 1;
            int a = ((rho << 7) | kgoff) ^ ((rho & 7) << 4);
            a = ((unsigned)gx < 32u) ? a : kgoff;       // OOB -> zeroed row 0 (xs=0 pad)
            const v8s bf0 = *(const v8s*)(smem + a);
#pragma unroll
            for (int m = 0; m < 4; ++m)
                acc[m][i] = __builtin_amdgcn_mfma_f32_16x16x32_bf16(af[m][0], bf0, acc[m][i], 0, 0, 0);
            const v8s bf1 = *(const v8s*)(smem + (a ^ 64));
#pragma unroll
            for (int m = 0; m < 4; ++m)
                acc[m][i] = __builtin_amdgcn_mfma_f32_16x16x32_bf16(af[m][1], bf1, acc[m][i], 0, 0, 0);
        }
    }
    // epilogue -> X3g [768][64c]
#pragma unroll
    for (int m = 0; m < 4; ++m) {
        const float* bp = b2 + m * 16 + kg * 4;
        const float bb0 = bp[0], bb1 = bp[1], bb2 = bp[2], bb3 = bp[3];
#pragma unroll
        for (int i = 0; i < 3; ++i) {
            const float v0 = fmaxf(acc[m][i][0] + bb0, 0.f);
            const float v1 = fmaxf(acc[m][i][1] + bb1, 0.f);
            const float v2 = fmaxf(acc[m][i][2] + bb2, 0.f);
            const float v3 = fmaxf(acc[m][i][3] + bb3, 0.f);
            uint2 pk;
            pk.x = pkbf(v0, v1);
            pk.y = pkbf(v2, v3);
            const int p = (x0 + lx[i]) * 24 + ly[i];
            *(uint2*)(x3g + p * 128 + (m * 16 + kg * 4) * 2) = pk;
        }
    }
}

// ======================= Kernel D: gather + MLP + store =======================
// grid 512 (sample), TPB 512. LDS: Ya/Yb f32 = 32,768B.
__global__ __launch_bounds__(512)
void k_gather_mlp(const int* __restrict__ rpos,
                  const float* __restrict__ rooms,
                  const float* __restrict__ rw0, const float* __restrict__ rb0,
                  const float* __restrict__ rw1, const float* __restrict__ rb1,
                  const float* __restrict__ rw2, const float* __restrict__ rb2,
                  const uint8_t* __restrict__ act,
                  float* __restrict__ out)
{
    __shared__ __align__(16) uint8_t smem[32768];
    const int tid = threadIdx.x, n = blockIdx.x;
    const int* rp = rpos + n * 128;
    const uint8_t* x3g = act + ACT_BASE + (size_t)n * SLOT_BYTES;   // [768][64c]

    // ---- gather: thread (gr = tid>>3, gg = tid&7) -> 8 channels of Y[gr] ----
    const int gr = tid >> 3, gg = tid & 7;
    {
        const int pxr = rp[gr * 2], pyr = rp[gr * 2 + 1];
        const float* rr = rooms + gr * 324;
        float s0=0,s1=0,s2=0,s3=0,s4=0,s5=0,s6=0,s7=0;
#pragma unroll
        for (int ci = 0; ci < 6; ++ci)
#pragma unroll
            for (int cj = 0; cj < 6; ++cj) {
                const float mv = rr[ci * 6 + cj];
                if (mv != 0.f) {
                    const int p = (pxr + ci) * 24 + pyr + cj;
                    const v8s v = *(const v8s*)(x3g + p * 128 + gg * 16);
                    s0 = fmaf(b2f((uint16_t)v[0]), mv, s0);
                    s1 = fmaf(b2f((uint16_t)v[1]), mv, s1);
                    s2 = fmaf(b2f((uint16_t)v[2]), mv, s2);
                    s3 = fmaf(b2f((uint16_t)v[3]), mv, s3);
                    s4 = fmaf(b2f((uint16_t)v[4]), mv, s4);
                    s5 = fmaf(b2f((uint16_t)v[5]), mv, s5);
                    s6 = fmaf(b2f((uint16_t)v[6]), mv, s6);
                    s7 = fmaf(b2f((uint16_t)v[7]), mv, s7);
                }
            }
        const int base = gr * 256 + gg * 32;
        const int swz = (gr & 7) << 4;
        *(v4f*)(smem + (base ^ swz))        = (v4f){s0, s1, s2, s3};
        *(v4f*)(smem + ((base + 16) ^ swz)) = (v4f){s4, s5, s6, s7};
    }
    __syncthreads();

    // ---- MLP: 3x (64x64), 512 threads x 8 outputs, chunked accumulation ----
    const int og = tid >> 6, r = tid & 63;
    const int ogs = __builtin_amdgcn_readfirstlane(og);
    const int swz = (r & 7) << 4;
#define MLP_LAYER(INOFF, OUTOFF, W, B, RELU)                                   \
    {                                                                          \
        float acc[8];                                                          \
        _Pragma("unroll")                                                      \
        for (int oo = 0; oo < 8; ++oo) acc[oo] = (B)[ogs * 8 + oo];            \
        const float* Wb = (W) + ogs * 8 * 64;                                  \
        _Pragma("unroll")                                                      \
        for (int cg = 0; cg < 16; ++cg) {                                      \
            const v4f v = *(const v4f*)(smem + (INOFF) + ((r * 256 + cg * 16) ^ swz)); \
            _Pragma("unroll")                                                  \
            for (int oo = 0; oo < 8; ++oo) {                                   \
                const float* wr = Wb + oo * 64 + cg * 4;                       \
                acc[oo] = fmaf(wr[0], v[0], acc[oo]);                          \
                acc[oo] = fmaf(wr[1], v[1], acc[oo]);                          \
                acc[oo] = fmaf(wr[2], v[2], acc[oo]);                          \
                acc[oo] = fmaf(wr[3], v[3], acc[oo]);                          \
            }                                                                  \
        }                                                                      \
        if (RELU) {                                                            \
            _Pragma("unroll")                                                  \
            for (int oo = 0; oo < 8; ++oo) acc[oo] = fmaxf(acc[oo], 0.f);      \
        }                                                                      \
        __syncthreads();                                                       \
        *(v4f*)(smem + (OUTOFF) + ((r * 256 + ogs * 32) ^ swz)) =              \
            (v4f){acc[0], acc[1], acc[2], acc[3]};                             \
        *(v4f*)(smem + (OUTOFF) + ((r * 256 + ogs * 32 + 16) ^ swz)) =         \
            (v4f){acc[4], acc[5], acc[6], acc[7]};                             \
        __syncthreads();                                                       \
    }
    MLP_LAYER(0,     16384, rw0, rb0, true)
    MLP_LAYER(16384, 0,     rw1, rb1, true)
    MLP_LAYER(0,     16384, rw2, rb2, false)
#undef MLP_LAYER

    // ---- coalesced store: out[n][r][oc] ----
    {
        const int rr2 = tid >> 3, cg = tid & 7;
        const int sw2 = (rr2 & 7) << 4;
        const v4f a0 = *(const v4f*)(smem + 16384 + ((rr2 * 256 + cg * 32) ^ sw2));
        const v4f a1 = *(const v4f*)(smem + 16384 + ((rr2 * 256 + cg * 32 + 16) ^ sw2));
        *(v4f*)(out + n * 4096 + rr2 * 64 + cg * 8)     = a0;
        *(v4f*)(out + n * 4096 + rr2 * 64 + cg * 8 + 4) = a1;
    }
}

// ======================= fallback: round-8 fused kernel =======================
#define X0_OFF 0
#define X1_OFF 106496
#define X2_OFF 0
#define X3_OFF 106496
#define SMEM_BYTES 159744

template<int MT, int KF, int TAPS, int KS, int PAD,
         int IN_OFF, int IN_SH, int IN_ROWS, int WS_BASE, int MT_TOT>
__device__ __forceinline__ void conv_core3(const uint8_t* smem, const v8s* __restrict__ wsv,
                                           int l, const int* px, const int* py,
                                           v4f (&acc)[MT][3])
{
    const int kgoff = ((l >> 4) << 4);
    constexpr int MSK = (IN_SH == 7) ? 7 : 3;
    for (int t = 0; t < TAPS; ++t) {
        const int ky = t / KS, kx = t - ky * KS;
        const int dx = ky - PAD, dy = kx - PAD;
        v8s af[MT][KF];
#pragma unroll
        for (int m = 0; m < MT; ++m)
#pragma unroll
            for (int kf = 0; kf < KF; ++kf)
                af[m][kf] = wsv[WS_BASE + ((t * KF + kf) * MT_TOT + m) * 64 + l];
#pragma unroll
        for (int i = 0; i < 3; ++i) {
            const int xi = px[i] + dx;
            const int rowp = xi * IN_ROWS + py[i] + dy + PAD;
            int a = ((rowp << IN_SH) | kgoff) ^ ((rowp & MSK) << 4);
            a = ((unsigned)xi < 32u) ? a : kgoff;
            a += IN_OFF;
            const v8s bf0 = *(const v8s*)(smem + a);
#pragma unroll
            for (int m = 0; m < MT; ++m)
                acc[m][i] = __builtin_amdgcn_mfma_f32_16x16x32_bf16(af[m][0], bf0, acc[m][i], 0, 0, 0);
            if (KF == 2) {
                const v8s bf1 = *(const v8s*)(smem + (a ^ 64));
#pragma unroll
                for (int m = 0; m < MT; ++m)
                    acc[m][i] = __builtin_amdgcn_mfma_f32_16x16x32_bf16(af[m][1], bf1, acc[m][i], 0, 0, 0);
            }
        }
    }
}

template<int MTOT, int M0, int M1, int OUT_OFF, int OUT_SH, int OUT_ROWS, int OUT_PAD>
__device__ __forceinline__ void conv_epi3(uint8_t* smem, const float* __restrict__ bias,
                                          v4f (&acc)[MTOT][3], const int* px, const int* py, int kg)
{
    constexpr int MSK = (OUT_SH == 7) ? 7 : 3;
#pragma unroll
    for (int m = M0; m < M1; ++m) {
        const float* bp = bias + m * 16 + kg * 4;
        const float bb0 = bp[0], bb1 = bp[1], bb2 = bp[2], bb3 = bp[3];
#pragma unroll
        for (int i = 0; i < 3; ++i) {
            const float v0 = fmaxf(acc[m][i][0] + bb0, 0.f);
            const float v1 = fmaxf(acc[m][i][1] + bb1, 0.f);
            const float v2 = fmaxf(acc[m][i][2] + bb2, 0.f);
            const float v3 = fmaxf(acc[m][i][3] + bb3, 0.f);
            uint2 pk; pk.x = pkbf(v0, v1); pk.y = pkbf(v2, v3);
            const int rowp = px[i] * OUT_ROWS + py[i] + OUT_PAD;
            const int coff = (m - M0) * 32 + (kg << 3);
            const int a = OUT_OFF + (((rowp << OUT_SH) | coff) ^ ((rowp & MSK) << 4));
            *(uint2*)(smem + a) = pk;
        }
    }
}

__global__ __launch_bounds__(1024)
void fused_fallback(const int* __restrict__ rpos, const float* __restrict__ rooms,
                    const float* __restrict__ emb,
                    const float* __restrict__ b0, const float* __restrict__ b1,
                    const float* __restrict__ b2,
                    const float* __restrict__ rw0, const float* __restrict__ rb0,
                    const float* __restrict__ rw1, const float* __restrict__ rb1,
                    const float* __restrict__ rw2, const float* __restrict__ rb2,
                    const uint8_t* __restrict__ ws, float* __restrict__ out)
{
    __shared__ __align__(16) uint8_t smem[SMEM_BYTES];
    const int tid = threadIdx.x, n = blockIdx.x;
    const int* rp = rpos + n * 128;
    const v8s* wsv = (const v8s*)ws;

    if (tid < 768) {
        const int x = (tid * 2731) >> 16;
        const int y = tid - x * 24;
        float a[26];
#pragma unroll
        for (int c = 0; c < 26; ++c) a[c] = 0.f;
        a[9] = 1.f;
        for (int r = 0; r < 64; ++r) {
            const int ci = x - rp[2 * r], cj = y - rp[2 * r + 1];
            if ((unsigned)ci < 6u && (unsigned)cj < 6u) {
                const int cell = ci * 6 + cj;
                const float* rr = rooms + r * 324;
                const float m = rr[cell];
                if (m != 0.f) {
#pragma unroll
                    for (int c = 0; c < 9; ++c) a[c] += rr[c * 36 + cell];
                    const float* er = emb + r * 16;
#pragma unroll
                    for (int e = 0; e < 16; ++e) a[10 + e] = fmaf(er[e], m, a[10 + e]);
                }
            }
        }
        const int row = x * 28 + y + 2;
        const int swz = (row & 3) << 4;
#pragma unroll
        for (int cg = 0; cg < 4; ++cg) {
            float c0 = (cg*8+0 < 26) ? a[(cg*8+0 < 26) ? cg*8+0 : 0] : 0.f;
            float c1 = (cg*8+1 < 26) ? a[(cg*8+1 < 26) ? cg*8+1 : 0] : 0.f;
            float c2 = (cg*8+2 < 26) ? a[(cg*8+2 < 26) ? cg*8+2 : 0] : 0.f;
            float c3 = (cg*8+3 < 26) ? a[(cg*8+3 < 26) ? cg*8+3 : 0] : 0.f;
            float c4 = (cg*8+4 < 26) ? a[(cg*8+4 < 26) ? cg*8+4 : 0] : 0.f;
            float c5 = (cg*8+5 < 26) ? a[(cg*8+5 < 26) ? cg*8+5 : 0] : 0.f;
            float c6 = (cg*8+6 < 26) ? a[(cg*8+6 < 26) ? cg*8+6 : 0] : 0.f;
            float c7 = (cg*8+7 < 26) ? a[(cg*8+7 < 26) ? cg*8+7 : 0] : 0.f;
            uint2 p0, p1;
            p0.x = pkbf(c0, c1); p0.y = pkbf(c2, c3);
            p1.x = pkbf(c4, c5); p1.y = pkbf(c6, c7);
            const int a0 = X0_OFF + (((row << 6) | (cg << 4)) ^ swz);
            *(uint2*)(smem + a0)     = p0;
            *(uint2*)(smem + a0 + 8) = p1;
        }
    } else {
        const int base = (tid - 768) * 2;
#pragma unroll
        for (int k = 0; k < 2; ++k) {
            const int u = base + k;
            const int rowi = u >> 2, slot = u & 3;
            const int x = rowi >> 2, yp = rowi & 3;
            const int row = x * 28 + ((yp < 2) ? yp : yp + 24);
            *(v8s*)(smem + X0_OFF + (((row << 6) | (slot << 4)) ^ ((row & 3) << 4))) =
                (v8s){0,0,0,0,0,0,0,0};
        }
    }
    __syncthreads();

    const int l = tid & 63, wv = tid >> 6, kg = l >> 4;
    int px[3], py[3];
#pragma unroll
    for (int i = 0; i < 3; ++i) {
        const int p = (wv + 16 * i) * 16 + (l & 15);
        const int x = (p * 2731) >> 16;
        px[i] = x; py[i] = p - x * 24;
    }
    {
        if (tid < 256) {
            const int rowi = tid >> 2, slot = tid & 3;
            const int x = rowi >> 1;
            const int rowp = x * 26 + ((rowi & 1) ? 25 : 0);
            *(v8s*)(smem + X1_OFF + (((rowp << 6) | (slot << 4)) ^ ((rowp & 3) << 4))) =
                (v8s){0,0,0,0,0,0,0,0};
        }
        v4f acc[2][3];
#pragma unroll
        for (int m = 0; m < 2; ++m)
#pragma unroll
            for (int i = 0; i < 3; ++i) acc[m][i] = (v4f){0.f,0.f,0.f,0.f};
        conv_core3<2,1,25,5,2, X0_OFF,6,28, WS0_U,2>(smem, wsv, l, px, py, acc);
        conv_epi3<2,0,2, X1_OFF,6,26,1>(smem, b0, acc, px, py, kg);
    }
    __syncthreads();
    {
        if (tid < 512) {
            const int rowi = tid >> 3, slot = tid & 7;
            const int x = rowi >> 1;
            const int rowp = x * 26 + ((rowi & 1) ? 25 : 0);
            *(v8s*)(smem + X2_OFF + (((rowp << 7) | (slot << 4)) ^ ((rowp & 7) << 4))) =
                (v8s){0,0,0,0,0,0,0,0};
        }
        v4f acc[4][3];
#pragma unroll
        for (int m = 0; m < 4; ++m)
#pragma unroll
            for (int i = 0; i < 3; ++i) acc[m][i] = (v4f){0.f,0.f,0.f,0.f};
        conv_core3<4,1,9,3,1, X1_OFF,6,26, WS1_U,4>(smem, wsv, l, px, py, acc);
        conv_epi3<4,0,4, X2_OFF,7,26,1>(smem, b1, acc, px, py, kg);
    }
    __syncthreads();
    float yregA[8], yregB[8];
    {
        v4f acc[4][3];
#pragma unroll
        for (int m = 0; m < 4; ++m)
#pragma unroll
            for (int i = 0; i < 3; ++i) acc[m][i] = (v4f){0.f,0.f,0.f,0.f};
        conv_core3<4,2,9,3,1, X2_OFF,7,26, WS2_U,4>(smem, wsv, l, px, py, acc);
        conv_epi3<4,0,2, X3_OFF,6,24,0>(smem, b2, acc, px, py, kg);
        __syncthreads();
        if (tid < 256) {
            const int gr = tid >> 2, gl = tid & 3;
            const int pxr = rp[gr * 2], pyr = rp[gr * 2 + 1];
            const float* rr = rooms + gr * 324;
            float s[8];
#pragma unroll
            for (int k = 0; k < 8; ++k) s[k] = 0.f;
#pragma unroll
            for (int ci = 0; ci < 6; ++ci)
#pragma unroll
                for (int cj = 0; cj < 6; ++cj) {
                    const float mv = rr[ci * 6 + cj];
                    if (mv != 0.f) {
                        const int p = (pxr + ci) * 24 + pyr + cj;
                        const int a = X3_OFF + (((p << 6) | (gl << 4)) ^ ((p & 3) << 4));
                        const v8s v = *(const v8s*)(smem + a);
#pragma unroll
                        for (int k = 0; k < 8; ++k)
                            s[k] = fmaf(b2f((uint16_t)v[k]), mv, s[k]);
                    }
                }
#pragma unroll
            for (int k = 0; k < 8; ++k) yregA[k] = s[k];
        }
        __syncthreads();
        conv_epi3<4,2,4, X3_OFF,6,24,0>(smem, b2, acc, px, py, kg);
        __syncthreads();
        if (tid < 256) {
            const int gr = tid >> 2, gl = tid & 3;
            const int pxr = rp[gr * 2], pyr = rp[gr * 2 + 1];
            const float* rr = rooms + gr * 324;
            float s[8];
#pragma unroll
            for (int k = 0; k < 8; ++k) s[k] = 0.f;
#pragma unroll
            for (int ci = 0; ci < 6; ++ci)
#pragma unroll
                for (int cj = 0; cj < 6; ++cj) {
                    const float mv = rr[ci * 6 + cj];
                    if (mv != 0.f) {
                        const int p = (pxr + ci) * 24 + pyr + cj;
                        const int a = X3_OFF + (((p << 6) | (gl << 4)) ^ ((p & 3) << 4));
                        const v8s v = *(const v8s*)(smem + a);
#pragma unroll
                        for (int k = 0; k < 8; ++k)
                            s[k] = fmaf(b2f((uint16_t)v[k]), mv, s[k]);
                    }
                }
#pragma unroll
            for (int k = 0; k < 8; ++k) yregB[k] = s[k];
        }
        __syncthreads();
    }
    if (tid < 256) {
        const int gr = tid >> 2, gl = tid & 3;
        const int swz = (gr & 7) << 4;
        const int baseA = gr * 256 + gl * 32;
        const int baseB = baseA + 128;
        *(v4f*)(smem + (baseA ^ swz))        = (v4f){yregA[0], yregA[1], yregA[2], yregA[3]};
        *(v4f*)(smem + ((baseA + 16) ^ swz)) = (v4f){yregA[4], yregA[5], yregA[6], yregA[7]};
        *(v4f*)(smem + (baseB ^ swz))        = (v4f){yregB[0], yregB[1], yregB[2], yregB[3]};
        *(v4f*)(smem + ((baseB + 16) ^ swz)) = (v4f){yregB[4], yregB[5], yregB[6], yregB[7]};
    }
    __syncthreads();
    {
        const int og = tid >> 6, r = tid & 63;
        const int ogs = __builtin_amdgcn_readfirstlane(og);
        const int swz = (r & 7) << 4;
#define FMLP(INOFF, OUTOFF, W, B, RELU)                                        \
        {                                                                      \
            float acc[4];                                                      \
            _Pragma("unroll")                                                  \
            for (int oo = 0; oo < 4; ++oo) acc[oo] = (B)[ogs * 4 + oo];        \
            const float* Wb = (W) + ogs * 4 * 64;                              \
            _Pragma("unroll")                                                  \
            for (int cg = 0; cg < 16; ++cg) {                                  \
                const v4f v = *(const v4f*)(smem + (INOFF) + ((r * 256 + cg * 16) ^ swz)); \
                _Pragma("unroll")                                              \
                for (int oo = 0; oo < 4; ++oo) {                               \
                    const float* wr = Wb + oo * 64 + cg * 4;                   \
                    acc[oo] = fmaf(wr[0], v[0], acc[oo]);                      \
                    acc[oo] = fmaf(wr[1], v[1], acc[oo]);                      \
                    acc[oo] = fmaf(wr[2], v[2], acc[oo]);                      \
                    acc[oo] = fmaf(wr[3], v[3], acc[oo]);                      \
                }                                                              \
            }                                                                  \
            if (RELU) { _Pragma("unroll")                                      \
                for (int oo = 0; oo < 4; ++oo) acc[oo] = fmaxf(acc[oo], 0.f); }\
            __syncthreads();                                                   \
            *(v4f*)(smem + (OUTOFF) + ((r * 256 + ogs * 16) ^ swz)) =          \
                (v4f){acc[0], acc[1], acc[2], acc[3]};                         \
            __syncthreads();                                                   \
        }
        FMLP(0,     16384, rw0, rb0, true)
        FMLP(16384, 0,     rw1, rb1, true)
        FMLP(0,     16384, rw2, rb2, false)
#undef FMLP
        const int rr2 = tid >> 4, cg = tid & 15;
        const int sw2 = (rr2 & 7) << 4;
        const v4f v = *(const v4f*)(smem + 16384 + ((rr2 * 256 + cg * 16) ^ sw2));
        *(v4f*)(out + n * 4096 + rr2 * 64 + cg * 4) = v;
    }
}

// ======================= launch =======================
extern "C" void kernel_launch(void* const* d_in, const int* in_sizes, int n_in,
                              void* d_out, int out_size, void* d_ws, size_t ws_size,
                              hipStream_t stream) {
    const int*   rpos  = (const int*)  d_in[0];
    const float* rooms = (const float*)d_in[1];
    const float* emb   = (const float*)d_in[2];
    const float* w0    = (const float*)d_in[3];
    const float* b0    = (const float*)d_in[4];
    const float* w1    = (const float*)d_in[5];
    const float* b1    = (const float*)d_in[6];
    const float* w2    = (const float*)d_in[7];
    const float* b2    = (const float*)d_in[8];
    const float* rw0   = (const float*)d_in[9];
    const float* rb0   = (const float*)d_in[10];
    const float* rw1   = (const float*)d_in[11];
    const float* rb1   = (const float*)d_in[12];
    const float* rw2   = (const float*)d_in[13];
    const float* rb2   = (const float*)d_in[14];
    float* out = (float*)d_out;
    uint8_t* ws = (uint8_t*)d_ws;

    const int n = in_sizes[0] / 128;   // samples (512)
    const size_t need = (size_t)ACT_BASE + (size_t)n * SLOT_BYTES;

    hipLaunchKernelGGL(prep_weights, dim3((WS_UNITS + 255) / 256), dim3(256), 0, stream,
                       w0, w1, w2, ws);
    if (ws_size >= need) {
        hipLaunchKernelGGL(k_scatter_conv0, dim3(n), dim3(512), 0, stream,
                           rpos, rooms, emb, b0, ws, ws);
        hipLaunchKernelGGL(k_conv1, dim3(n * 2), dim3(512), 0, stream, b1, ws, ws);
        hipLaunchKernelGGL(k_conv2, dim3(n * 4), dim3(256), 0, stream, b2, ws, ws);
        hipLaunchKernelGGL(k_gather_mlp, dim3(n), dim3(512), 0, stream,
                           rpos, rooms, rw0, rb0, rw1, rb1, rw2, rb2, ws, out);
    } else {
        hipLaunchKernelGGL(fused_fallback, dim3(n), dim3(1024), 0, stream,
                           rpos, rooms, emb, b0, b1, b2,
                           rw0, rb0, rw1, rb1, rw2, rb2, ws, out);
    }
}

// Round 10
// 155.855 us; speedup vs baseline: 1.4015x; 1.4015x over previous
//
#include <hip/hip_runtime.h>
#include <hip/hip_bf16.h>
#include <stdint.h>

typedef short v8s __attribute__((ext_vector_type(8)));
typedef float v4f __attribute__((ext_vector_type(4)));

// ---------------- common helpers ----------------
__device__ __forceinline__ uint16_t f2b(float f) {
    __hip_bfloat16 h = __float2bfloat16(f);
    return *reinterpret_cast<uint16_t*>(&h);
}
__device__ __forceinline__ uint32_t pkbf(float lo, float hi) {
    return (uint32_t)f2b(lo) | ((uint32_t)f2b(hi) << 16);
}
__device__ __forceinline__ float b2f(uint16_t h) {
    return __uint_as_float(((uint32_t)h) << 16);
}

// ws weight-fragment bases (16B units): conv0 50 frags, conv1 36, conv2 72 (x64 lanes)
#define WS0_U 0
#define WS1_U 3200
#define WS2_U 5504
#define WS_UNITS 10112
#define WS_W_BYTES (WS_UNITS * 16)          // 161,792

// activation slots (per sample): slotA = X1 [768][64B] then X3 [768][128B] (98,304B)
//                                slotB = X2 planar [2][768][64B]           (98,304B)
#define SLOT_BYTES 196608
#define ACT_BASE   WS_W_BYTES

// ---------------- weight prep: pack A-fragments (bf16) into d_ws ----------------
__global__ void prep_weights(const float* __restrict__ w0,
                             const float* __restrict__ w1,
                             const float* __restrict__ w2,
                             uint8_t* __restrict__ ws)
{
    int u = blockIdx.x * 256 + threadIdx.x;
    if (u >= WS_UNITS) return;
    int l = u & 63, fid = u >> 6;
    const float* src; int IC, KS_, t, kf, m;
    if (fid < 50)      { src = w0; IC = 26; KS_ = 5; t = fid >> 1; kf = 0; m = fid & 1; }
    else if (fid < 86) { int v = fid - 50; src = w1; IC = 32; KS_ = 3; t = v >> 2; kf = 0; m = v & 3; }
    else               { int v = fid - 86; src = w2; IC = 64; KS_ = 3; t = v >> 3; kf = (v >> 2) & 1; m = v & 3; }
    int oc = m * 16 + (l & 15);
    int kb = kf * 32 + ((l >> 4) * 8);
    int ky = t / KS_, kx = t - ky * KS_;
    v8s out;
#pragma unroll
    for (int j = 0; j < 8; ++j) {
        int k = kb + j;
        float v = (k < IC) ? src[((oc * IC + k) * KS_ + ky) * KS_ + kx] : 0.f;
        out[j] = (short)f2b(v);
    }
    ((v8s*)ws)[u] = out;
}

// ---------------- conv core, 6 tiles/wave (runtime oc-block base mb) ----------------
template<int MT, int TAPS, int KS, int PAD, int IN_SH, int IN_ROWS,
         int WS_BASE, int MT_TOT>
__device__ __forceinline__ void conv_core6(const uint8_t* smem, const v8s* __restrict__ wsv,
                                           int l, int mb, const int* px, const int* py,
                                           v4f (&acc)[MT][6])
{
    const int kgoff = ((l >> 4) << 4);
    constexpr int MSK = (IN_SH == 7) ? 7 : 3;
    for (int t = 0; t < TAPS; ++t) {
        const int ky = t / KS, kx = t - ky * KS;
        const int dx = ky - PAD, dy = kx - PAD;
        v8s af[MT];
#pragma unroll
        for (int m = 0; m < MT; ++m)
            af[m] = wsv[WS_BASE + (t * MT_TOT + mb + m) * 64 + l];
#pragma unroll
        for (int i = 0; i < 6; ++i) {
            const int xi = px[i] + dx;
            const int rowp = xi * IN_ROWS + py[i] + dy + PAD;
            int a = ((rowp << IN_SH) | kgoff) ^ ((rowp & MSK) << 4);
            a = ((unsigned)xi < 32u) ? a : kgoff;            // x OOB -> zeroed row 0
            const v8s bf0 = *(const v8s*)(smem + a);
#pragma unroll
            for (int m = 0; m < MT; ++m)
                acc[m][i] = __builtin_amdgcn_mfma_f32_16x16x32_bf16(af[m], bf0, acc[m][i], 0, 0, 0);
        }
    }
}

// epilogue into LDS [768 p][64B] swizzled (p&3)<<4, bias base bb (oc16-blocks)
template<int MT>
__device__ __forceinline__ void epi6_lds(uint8_t* smem, const float* __restrict__ bias, int bb,
                                         v4f (&acc)[MT][6], const int* px, const int* py, int kg)
{
#pragma unroll
    for (int m = 0; m < MT; ++m) {
        const float* bp = bias + (bb + m) * 16 + kg * 4;
        const float bb0 = bp[0], bb1 = bp[1], bb2 = bp[2], bb3 = bp[3];
#pragma unroll
        for (int i = 0; i < 6; ++i) {
            const float v0 = fmaxf(acc[m][i][0] + bb0, 0.f);
            const float v1 = fmaxf(acc[m][i][1] + bb1, 0.f);
            const float v2 = fmaxf(acc[m][i][2] + bb2, 0.f);
            const float v3 = fmaxf(acc[m][i][3] + bb3, 0.f);
            uint2 pk; pk.x = pkbf(v0, v1); pk.y = pkbf(v2, v3);
            const int p = px[i] * 24 + py[i];
            const int coff = (m * 16 + kg * 4) * 2;          // byte offset of 4 channels
            *(uint2*)(smem + (((p << 6) | coff) ^ ((p & 3) << 4))) = pk;
        }
    }
}

// ======================= Kernel A: scatter + conv0 =======================
// grid 512, TPB 512. LDS: X0 [896 rows][64B] swz (row&3)<<4 = 57,344B.
__global__ __launch_bounds__(512, 4)
void k_scatter_conv0(const int* __restrict__ rpos,
                     const float* __restrict__ rooms,
                     const float* __restrict__ emb,
                     const float* __restrict__ b0,
                     const uint8_t* __restrict__ ws,
                     uint8_t* __restrict__ act)
{
    __shared__ __align__(16) uint8_t smem[57344];
    const int tid = threadIdx.x, n = blockIdx.x;
    const int* rp = rpos + n * 128;
    const v8s* wsv = (const v8s*)ws;
    uint8_t* x1g = act + ACT_BASE + (size_t)n * SLOT_BYTES;        // [768][64B]

    // ---- scatter: one padded row per thread ----
    for (int u = tid; u < 896; u += 512) {
        const int x = (u * 2341) >> 16;            // u / 28
        const int yp = u - x * 28;
        const int swz = (u & 3) << 4;
        if (yp >= 2 && yp < 26) {
            const int y = yp - 2;
            float a[26];
#pragma unroll
            for (int c = 0; c < 26; ++c) a[c] = 0.f;
            a[9] = 1.f;
            for (int r = 0; r < 64; ++r) {
                const int ci = x - rp[2 * r], cj = y - rp[2 * r + 1];
                if ((unsigned)ci < 6u && (unsigned)cj < 6u) {
                    const int cell = ci * 6 + cj;
                    const float* rr = rooms + r * 324;
                    const float mv = rr[cell];
                    if (mv != 0.f) {
#pragma unroll
                        for (int c = 0; c < 9; ++c) a[c] += rr[c * 36 + cell];
                        const float* er = emb + r * 16;
#pragma unroll
                        for (int e = 0; e < 16; ++e) a[10 + e] = fmaf(er[e], mv, a[10 + e]);
                    }
                }
            }
#pragma unroll
            for (int cg = 0; cg < 4; ++cg) {
                float c0 = (cg * 8 + 0 < 26) ? a[(cg * 8 + 0 < 26) ? cg * 8 + 0 : 0] : 0.f;
                float c1 = (cg * 8 + 1 < 26) ? a[(cg * 8 + 1 < 26) ? cg * 8 + 1 : 0] : 0.f;
                float c2 = (cg * 8 + 2 < 26) ? a[(cg * 8 + 2 < 26) ? cg * 8 + 2 : 0] : 0.f;
                float c3 = (cg * 8 + 3 < 26) ? a[(cg * 8 + 3 < 26) ? cg * 8 + 3 : 0] : 0.f;
                float c4 = (cg * 8 + 4 < 26) ? a[(cg * 8 + 4 < 26) ? cg * 8 + 4 : 0] : 0.f;
                float c5 = (cg * 8 + 5 < 26) ? a[(cg * 8 + 5 < 26) ? cg * 8 + 5 : 0] : 0.f;
                float c6 = (cg * 8 + 6 < 26) ? a[(cg * 8 + 6 < 26) ? cg * 8 + 6 : 0] : 0.f;
                float c7 = (cg * 8 + 7 < 26) ? a[(cg * 8 + 7 < 26) ? cg * 8 + 7 : 0] : 0.f;
                uint2 p0, p1;
                p0.x = pkbf(c0, c1); p0.y = pkbf(c2, c3);
                p1.x = pkbf(c4, c5); p1.y = pkbf(c6, c7);
                const int a0 = (((u << 6) | (cg << 4)) ^ swz);
                *(uint2*)(smem + a0)     = p0;
                *(uint2*)(smem + a0 + 8) = p1;
            }
        } else {
#pragma unroll
            for (int cg = 0; cg < 4; ++cg)
                *(v8s*)(smem + (((u << 6) | (cg << 4)) ^ swz)) = (v8s){0,0,0,0,0,0,0,0};
        }
    }
    __syncthreads();

    // ---- conv0: 26->32, 5x5, MT=2, 6 tiles/wave ----
    const int l = tid & 63, wv = tid >> 6, kg = l >> 4;
    int px[6], py[6];
#pragma unroll
    for (int i = 0; i < 6; ++i) {
        const int p = (wv * 6 + i) * 16 + (l & 15);
        const int x = (p * 2731) >> 16;
        px[i] = x; py[i] = p - x * 24;
    }
    v4f acc[2][6];
#pragma unroll
    for (int m = 0; m < 2; ++m)
#pragma unroll
        for (int i = 0; i < 6; ++i) acc[m][i] = (v4f){0.f, 0.f, 0.f, 0.f};
    conv_core6<2, 25, 5, 2, 6, 28, WS0_U, 2>(smem, wsv, l, 0, px, py, acc);
    __syncthreads();                               // X0 dead -> reuse LDS for output
    epi6_lds<2>(smem, b0, 0, acc, px, py, kg);
    __syncthreads();

    // ---- dense coalesced copy LDS -> X1 global (48KB) ----
    for (int u = tid; u < 3072; u += 512) {
        const int row = u >> 2, slot = u & 3;
        const v8s v = *(const v8s*)(smem + (((row << 6) | (slot << 4)) ^ ((row & 3) << 4)));
        *(v8s*)(x1g + (size_t)u * 16) = v;         // u*16 == row*64 + slot*16
    }
}

// ======================= Kernel B: conv1 (per oc-half) =======================
// grid 1024 (n = bid>>1, h = bid&1), TPB 512. LDS: X1 [832 rows][64B] swz&3 = 53,248B.
__global__ __launch_bounds__(512, 4)
void k_conv1(const float* __restrict__ b1,
             const uint8_t* __restrict__ ws,
             uint8_t* __restrict__ act)
{
    __shared__ __align__(16) uint8_t smem[53248];
    const int tid = threadIdx.x;
    const int n = blockIdx.x >> 1, h = blockIdx.x & 1;
    const v8s* wsv = (const v8s*)ws;
    const uint8_t* x1g = act + ACT_BASE + (size_t)n * SLOT_BYTES;                    // [768][64B]
    uint8_t*       x2g = act + ACT_BASE + (size_t)n * SLOT_BYTES + 98304 + h * 49152; // plane h

    // stage X1 -> LDS (insert y-pad rows)
    for (int u = tid; u < 3328; u += 512) {
        const int row = u >> 2, slot = u & 3;
        const int x = (row * 2521) >> 16;          // row / 26
        const int yp = row - x * 26;
        v8s v = {0,0,0,0,0,0,0,0};
        if (yp >= 1 && yp < 25) {
            const int p = x * 24 + yp - 1;
            v = *(const v8s*)(x1g + p * 64 + slot * 16);
        }
        *(v8s*)(smem + (((row << 6) | (slot << 4)) ^ ((row & 3) << 4))) = v;
    }
    __syncthreads();

    const int l = tid & 63, wv = tid >> 6, kg = l >> 4;
    int px[6], py[6];
#pragma unroll
    for (int i = 0; i < 6; ++i) {
        const int p = (wv * 6 + i) * 16 + (l & 15);
        const int x = (p * 2731) >> 16;
        px[i] = x; py[i] = p - x * 24;
    }
    v4f acc[2][6];
#pragma unroll
    for (int m = 0; m < 2; ++m)
#pragma unroll
        for (int i = 0; i < 6; ++i) acc[m][i] = (v4f){0.f, 0.f, 0.f, 0.f};
    conv_core6<2, 9, 3, 1, 6, 26, WS1_U, 4>(smem, wsv, l, 2 * h, px, py, acc);
    __syncthreads();                               // X1 dead -> reuse LDS
    epi6_lds<2>(smem, b1, 2 * h, acc, px, py, kg);
    __syncthreads();

    // dense copy LDS -> X2 plane h (48KB contiguous)
    for (int u = tid; u < 3072; u += 512) {
        const int row = u >> 2, slot = u & 3;
        const v8s v = *(const v8s*)(smem + (((row << 6) | (slot << 4)) ^ ((row & 3) << 4)));
        *(v8s*)(x2g + (size_t)u * 16) = v;
    }
}

// ======================= Kernel C: conv2 (per 8-wide x-slab) =======================
// grid 2048 (n = bid>>2, s = bid&3), TPB 256. LDS slab: [260 rho][128B] swz&7 = 33,280B.
__global__ __launch_bounds__(256, 4)
void k_conv2(const float* __restrict__ b2,
             const uint8_t* __restrict__ ws,
             uint8_t* __restrict__ act)
{
    __shared__ __align__(16) uint8_t smem[33280];
    const int tid = threadIdx.x;
    const int n = blockIdx.x >> 2, s = blockIdx.x & 3;
    const int x0 = s * 8;
    const v8s* wsv = (const v8s*)ws;
    const uint8_t* x2g = act + ACT_BASE + (size_t)n * SLOT_BYTES + 98304;   // planar [2][768][64B]
    uint8_t*       x3g = act + ACT_BASE + (size_t)n * SLOT_BYTES;           // [768][128B]

    // stage slab: rho = xs*26 + y', xs in [0,10) <-> gx = x0 + xs - 1; slot s8: plane s8>>2
    for (int u = tid; u < 2080; u += 256) {
        const int rho = u >> 3, slot = u & 7;
        const int xs = (rho * 2521) >> 16;         // rho / 26
        const int yp = rho - xs * 26;
        const int gx = x0 + xs - 1;
        v8s v = {0,0,0,0,0,0,0,0};
        if ((unsigned)gx < 32u && yp >= 1 && yp < 25) {
            const int p = gx * 24 + yp - 1;
            v = *(const v8s*)(x2g + (slot >> 2) * 49152 + p * 64 + (slot & 3) * 16);
        }
        *(v8s*)(smem + (((rho << 7) | (slot << 4)) ^ ((rho & 7) << 4))) = v;
    }
    __syncthreads();

    // conv2: 64->64, 3x3, MT=4, KF=2, 3 tiles/wave over 192 local pixels
    const int l = tid & 63, wv = tid >> 6, kg = l >> 4;
    const int kgoff = kg << 4;
    int lx[3], ly[3];
#pragma unroll
    for (int i = 0; i < 3; ++i) {
        const int p = (wv * 3 + i) * 16 + (l & 15);     // 0..191
        const int x = (p * 2731) >> 16;
        lx[i] = x; ly[i] = p - x * 24;
    }
    v4f acc[4][3];
#pragma unroll
    for (int m = 0; m < 4; ++m)
#pragma unroll
        for (int i = 0; i < 3; ++i) acc[m][i] = (v4f){0.f, 0.f, 0.f, 0.f};

    for (int t = 0; t < 9; ++t) {
        const int ky = t / 3, kx = t - ky * 3;
        const int dx = ky - 1, dy = kx - 1;
        v8s af[4][2];
#pragma unroll
        for (int m = 0; m < 4; ++m)
#pragma unroll
            for (int kf = 0; kf < 2; ++kf)
                af[m][kf] = wsv[WS2_U + ((t * 2 + kf) * 4 + m) * 64 + l];
#pragma unroll
        for (int i = 0; i < 3; ++i) {
            const int gx = x0 + lx[i] + dx;
            const int rho = (lx[i] + dx + 1) * 26 + ly[i] + dy + 1;
            int a = ((rho << 7) | kgoff) ^ ((rho & 7) << 4);
            a = ((unsigned)gx < 32u) ? a : kgoff;       // OOB -> zeroed row 0
            const v8s bf0 = *(const v8s*)(smem + a);
#pragma unroll
            for (int m = 0; m < 4; ++m)
                acc[m][i] = __builtin_amdgcn_mfma_f32_16x16x32_bf16(af[m][0], bf0, acc[m][i], 0, 0, 0);
            const v8s bf1 = *(const v8s*)(smem + (a ^ 64));
#pragma unroll
            for (int m = 0; m < 4; ++m)
                acc[m][i] = __builtin_amdgcn_mfma_f32_16x16x32_bf16(af[m][1], bf1, acc[m][i], 0, 0, 0);
        }
    }
    __syncthreads();                               // slab staging dead -> reuse LDS
    // epilogue into LDS [192 lp][128B] swz (lp&7)<<4 (24,576B)
#pragma unroll
    for (int m = 0; m < 4; ++m) {
        const float* bp = b2 + m * 16 + kg * 4;
        const float bb0 = bp[0], bb1 = bp[1], bb2 = bp[2], bb3 = bp[3];
#pragma unroll
        for (int i = 0; i < 3; ++i) {
            const float v0 = fmaxf(acc[m][i][0] + bb0, 0.f);
            const float v1 = fmaxf(acc[m][i][1] + bb1, 0.f);
            const float v2 = fmaxf(acc[m][i][2] + bb2, 0.f);
            const float v3 = fmaxf(acc[m][i][3] + bb3, 0.f);
            uint2 pk; pk.x = pkbf(v0, v1); pk.y = pkbf(v2, v3);
            const int lp = lx[i] * 24 + ly[i];
            const int coff = (m * 16 + kg * 4) * 2;
            *(uint2*)(smem + (((lp << 7) | coff) ^ ((lp & 7) << 4))) = pk;
        }
    }
    __syncthreads();

    // dense copy LDS -> X3 slab (24,576B contiguous)
    for (int u = tid; u < 1536; u += 256) {
        const int lp = u >> 3, slot = u & 7;
        const v8s v = *(const v8s*)(smem + (((lp << 7) | (slot << 4)) ^ ((lp & 7) << 4)));
        *(v8s*)(x3g + (size_t)(x0 * 24) * 128 + (size_t)u * 16) = v;
    }
}

// ======================= Kernel D: gather + MLP + store =======================
// grid 512, TPB 512. LDS: Ya/Yb f32 = 32,768B.
__global__ __launch_bounds__(512, 4)
void k_gather_mlp(const int* __restrict__ rpos,
                  const float* __restrict__ rooms,
                  const float* __restrict__ rw0, const float* __restrict__ rb0,
                  const float* __restrict__ rw1, const float* __restrict__ rb1,
                  const float* __restrict__ rw2, const float* __restrict__ rb2,
                  const uint8_t* __restrict__ act,
                  float* __restrict__ out)
{
    __shared__ __align__(16) uint8_t smem[32768];
    const int tid = threadIdx.x, n = blockIdx.x;
    const int* rp = rpos + n * 128;
    const uint8_t* x3g = act + ACT_BASE + (size_t)n * SLOT_BYTES;   // [768][128B]

    const int gr = tid >> 3, gg = tid & 7;
    {
        const int pxr = rp[gr * 2], pyr = rp[gr * 2 + 1];
        const float* rr = rooms + gr * 324;
        float s0=0,s1=0,s2=0,s3=0,s4=0,s5=0,s6=0,s7=0;
#pragma unroll
        for (int ci = 0; ci < 6; ++ci)
#pragma unroll
            for (int cj = 0; cj < 6; ++cj) {
                const float mv = rr[ci * 6 + cj];
                if (mv != 0.f) {
                    const int p = (pxr + ci) * 24 + pyr + cj;
                    const v8s v = *(const v8s*)(x3g + p * 128 + gg * 16);
                    s0 = fmaf(b2f((uint16_t)v[0]), mv, s0);
                    s1 = fmaf(b2f((uint16_t)v[1]), mv, s1);
                    s2 = fmaf(b2f((uint16_t)v[2]), mv, s2);
                    s3 = fmaf(b2f((uint16_t)v[3]), mv, s3);
                    s4 = fmaf(b2f((uint16_t)v[4]), mv, s4);
                    s5 = fmaf(b2f((uint16_t)v[5]), mv, s5);
                    s6 = fmaf(b2f((uint16_t)v[6]), mv, s6);
                    s7 = fmaf(b2f((uint16_t)v[7]), mv, s7);
                }
            }
        const int base = gr * 256 + gg * 32;
        const int swz = (gr & 7) << 4;
        *(v4f*)(smem + (base ^ swz))        = (v4f){s0, s1, s2, s3};
        *(v4f*)(smem + ((base + 16) ^ swz)) = (v4f){s4, s5, s6, s7};
    }
    __syncthreads();

    const int og = tid >> 6, r = tid & 63;
    const int ogs = __builtin_amdgcn_readfirstlane(og);
    const int swz = (r & 7) << 4;
#define MLP_LAYER(INOFF, OUTOFF, W, B, RELU)                                   \
    {                                                                          \
        float acc[8];                                                          \
        _Pragma("unroll")                                                      \
        for (int oo = 0; oo < 8; ++oo) acc[oo] = (B)[ogs * 8 + oo];            \
        const float* Wb = (W) + ogs * 8 * 64;                                  \
        _Pragma("unroll")                                                      \
        for (int cg = 0; cg < 16; ++cg) {                                      \
            const v4f v = *(const v4f*)(smem + (INOFF) + ((r * 256 + cg * 16) ^ swz)); \
            _Pragma("unroll")                                                  \
            for (int oo = 0; oo < 8; ++oo) {                                   \
                const float* wr = Wb + oo * 64 + cg * 4;                       \
                acc[oo] = fmaf(wr[0], v[0], acc[oo]);                          \
                acc[oo] = fmaf(wr[1], v[1], acc[oo]);                          \
                acc[oo] = fmaf(wr[2], v[2], acc[oo]);                          \
                acc[oo] = fmaf(wr[3], v[3], acc[oo]);                          \
            }                                                                  \
        }                                                                      \
        if (RELU) {                                                            \
            _Pragma("unroll")                                                  \
            for (int oo = 0; oo < 8; ++oo) acc[oo] = fmaxf(acc[oo], 0.f);      \
        }                                                                      \
        __syncthreads();                                                       \
        *(v4f*)(smem + (OUTOFF) + ((r * 256 + ogs * 32) ^ swz)) =              \
            (v4f){acc[0], acc[1], acc[2], acc[3]};                             \
        *(v4f*)(smem + (OUTOFF) + ((r * 256 + ogs * 32 + 16) ^ swz)) =         \
            (v4f){acc[4], acc[5], acc[6], acc[7]};                             \
        __syncthreads();                                                       \
    }
    MLP_LAYER(0,     16384, rw0, rb0, true)
    MLP_LAYER(16384, 0,     rw1, rb1, true)
    MLP_LAYER(0,     16384, rw2, rb2, false)
#undef MLP_LAYER

    {
        const int rr2 = tid >> 3, cg = tid & 7;
        const int sw2 = (rr2 & 7) << 4;
        const v4f a0 = *(const v4f*)(smem + 16384 + ((rr2 * 256 + cg * 32) ^ sw2));
        const v4f a1 = *(const v4f*)(smem + 16384 + ((rr2 * 256 + cg * 32 + 16) ^ sw2));
        *(v4f*)(out + n * 4096 + rr2 * 64 + cg * 8)     = a0;
        *(v4f*)(out + n * 4096 + rr2 * 64 + cg * 8 + 4) = a1;
    }
}

// ======================= launch =======================
extern "C" void kernel_launch(void* const* d_in, const int* in_sizes, int n_in,
                              void* d_out, int out_size, void* d_ws, size_t ws_size,
                              hipStream_t stream) {
    const int*   rpos  = (const int*)  d_in[0];
    const float* rooms = (const float*)d_in[1];
    const float* emb   = (const float*)d_in[2];
    const float* w0    = (const float*)d_in[3];
    const float* b0    = (const float*)d_in[4];
    const float* w1    = (const float*)d_in[5];
    const float* b1    = (const float*)d_in[6];
    const float* w2    = (const float*)d_in[7];
    const float* b2    = (const float*)d_in[8];
    const float* rw0   = (const float*)d_in[9];
    const float* rb0   = (const float*)d_in[10];
    const float* rw1   = (const float*)d_in[11];
    const float* rb1   = (const float*)d_in[12];
    const float* rw2   = (const float*)d_in[13];
    const float* rb2   = (const float*)d_in[14];
    float* out = (float*)d_out;
    uint8_t* ws = (uint8_t*)d_ws;

    const int n = in_sizes[0] / 128;   // samples (512)

    hipLaunchKernelGGL(prep_weights, dim3((WS_UNITS + 255) / 256), dim3(256), 0, stream,
                       w0, w1, w2, ws);
    hipLaunchKernelGGL(k_scatter_conv0, dim3(n), dim3(512), 0, stream,
                       rpos, rooms, emb, b0, ws, ws);
    hipLaunchKernelGGL(k_conv1, dim3(n * 2), dim3(512), 0, stream, b1, ws, ws);
    hipLaunchKernelGGL(k_conv2, dim3(n * 4), dim3(256), 0, stream, b2, ws, ws);
    hipLaunchKernelGGL(k_gather_mlp, dim3(n), dim3(512), 0, stream,
                       rpos, rooms, rw0, rb0, rw1, rb1, rw2, rb2, ws, out);
}